// Round 1
// baseline (250.368 us; speedup 1.0000x reference)
//
#include <hip/hip_runtime.h>
#include <hip/hip_bf16.h>
#include <cstdint>
#include <cstddef>

typedef __bf16 bf16_t;
typedef bf16_t bf16x8 __attribute__((ext_vector_type(8)));
typedef bf16_t bf16x4 __attribute__((ext_vector_type(4)));
typedef float  f32x4  __attribute__((ext_vector_type(4)));
typedef unsigned int u32;

#define BROWS 4096
#define NV    8192
#define KD    1024
#define BM 128
#define BN 128
#define BK 32

// async global->LDS, 16B per lane; LDS dst is wave-uniform base + lane*16
#define GLL(gsrc, ldst) \
  __builtin_amdgcn_global_load_lds((const __attribute__((address_space(1))) u32*)(gsrc), \
                                   (__attribute__((address_space(3))) u32*)(ldst), 16, 0, 0)

// ---------------- f32 -> bf16 conversion ----------------
__global__ void cvt_kernel(const float* __restrict__ src, bf16_t* __restrict__ dst, int n4) {
  int idx = blockIdx.x * blockDim.x + threadIdx.x;
  int stride = gridDim.x * blockDim.x;
  for (int i = idx; i < n4; i += stride) {
    float4 v = ((const float4*)src)[i];
    bf16x4 o;
    o[0] = (bf16_t)v.x; o[1] = (bf16_t)v.y; o[2] = (bf16_t)v.z; o[3] = (bf16_t)v.w;
    ((bf16x4*)dst)[i] = o;
  }
}

// ---------------- GEMM: expout = exp(E @ W^T + b), bf16 out ----------------
// m97 structure: 128x128 tile, BK=32, 4 waves (2x2), 4x4 16x16x32 frags/wave,
// linear LDS + global_load_lds width 16, 2 barriers per K-step.
__global__ __launch_bounds__(256)
void gemm_exp_kernel(const bf16_t* __restrict__ A, const bf16_t* __restrict__ B,
                     const float* __restrict__ bias, bf16_t* __restrict__ expout) {
  __shared__ bf16_t sA[BM][BK];   // 8 KB
  __shared__ bf16_t sB[BN][BK];   // 8 KB

  const int t    = threadIdx.x;
  const int lane = t & 63;
  const int wv   = t >> 6;

  // XCD-aware swizzle (2048 blocks % 8 == 0 -> simple form is bijective)
  int bid = blockIdx.x;
  int wg  = (bid & 7) * 256 + (bid >> 3);
  const int mt = wg >> 6;          // 0..31
  const int nt = wg & 63;          // 0..63
  const int row0 = mt * BM;
  const int col0 = nt * BN;

  // staging: thread t, chunk q in {0,1}: row=(q*256+t)/4, kelem=(t&3)*8
  const int srow = t >> 2;
  const int skel = (t & 3) * 8;
  const bf16_t* ap0 = A + (size_t)(row0 + srow) * KD + skel;
  const bf16_t* ap1 = ap0 + (size_t)64 * KD;
  const bf16_t* bp0 = B + (size_t)(col0 + srow) * KD + skel;
  const bf16_t* bp1 = bp0 + (size_t)64 * KD;
  // wave-uniform LDS bases (element offsets; HW adds lane*16B)
  bf16_t* sa0 = &sA[0][0] + (wv * 64) * 8;
  bf16_t* sa1 = &sA[0][0] + (256 + wv * 64) * 8;
  bf16_t* sb0 = &sB[0][0] + (wv * 64) * 8;
  bf16_t* sb1 = &sB[0][0] + (256 + wv * 64) * 8;

  const int wr = (wv >> 1) * 64;   // wave row origin in tile
  const int wc = (wv & 1) * 64;    // wave col origin in tile
  const int fr = lane & 15;
  const int fq = lane >> 4;

  f32x4 acc[4][4] = {};

  for (int k0 = 0; k0 < KD; k0 += BK) {
    GLL(ap0 + k0, sa0);
    GLL(ap1 + k0, sa1);
    GLL(bp0 + k0, sb0);
    GLL(bp1 + k0, sb1);
    __syncthreads();   // drains vmcnt, then barrier: LDS tiles ready

    bf16x8 af[4], bg[4];
#pragma unroll
    for (int i = 0; i < 4; ++i) {
      af[i] = *(const bf16x8*)&sA[wr + i * 16 + fr][fq * 8];
      bg[i] = *(const bf16x8*)&sB[wc + i * 16 + fr][fq * 8];
    }
#pragma unroll
    for (int i = 0; i < 4; ++i)
#pragma unroll
      for (int j = 0; j < 4; ++j)
        acc[i][j] = __builtin_amdgcn_mfma_f32_16x16x32_bf16(af[i], bg[j], acc[i][j], 0, 0, 0);
    __syncthreads();   // all waves done reading before next stage overwrites
  }

  // epilogue: D row=(lane>>4)*4+r, col=lane&15 (measured m89/m91 mapping)
#pragma unroll
  for (int j = 0; j < 4; ++j) {
    const int col = col0 + wc + j * 16 + fr;
    const float bb = bias[col];
#pragma unroll
    for (int i = 0; i < 4; ++i) {
      const int rowb = row0 + wr + i * 16 + fq * 4;
#pragma unroll
      for (int r = 0; r < 4; ++r) {
        // exp(x) = exp2(x * log2(e)); logits bounded ~|4| for this input dist
        float e = exp2f((acc[i][j][r] + bb) * 1.44269504088896340736f);
        expout[(size_t)(rowb + r) * NV + col] = (bf16_t)e;
      }
    }
  }
}

// ---------------- per-row marginals + normalize ----------------
__global__ __launch_bounds__(256)
void marginal_kernel(const bf16_t* __restrict__ expbuf, const int* __restrict__ vstate,
                     float* __restrict__ out) {
  const int b = blockIdx.x;
  const int t = threadIdx.x;
  const int lane = t & 63;
  const int wv = t >> 6;

  float acc[48];
#pragma unroll
  for (int i = 0; i < 48; ++i) acc[i] = 0.f;

  const bf16_t* row = expbuf + (size_t)b * NV;
  for (int j = t; j < NV; j += 256) {
    const float e = (float)row[j];
    const int v = vstate[j];
#pragma unroll
    for (int c = 0; c < 6; ++c) {
      const int d = (v >> (15 - 3 * c)) & 7;
#pragma unroll
      for (int dd = 0; dd < 8; ++dd)
        acc[c * 8 + dd] += (d == dd) ? e : 0.f;
    }
  }

  // full-wave butterfly reduce each of the 48 accumulators
#pragma unroll
  for (int i = 0; i < 48; ++i) {
    float v = acc[i];
    v += __shfl_xor(v, 32); v += __shfl_xor(v, 16); v += __shfl_xor(v, 8);
    v += __shfl_xor(v, 4);  v += __shfl_xor(v, 2);  v += __shfl_xor(v, 1);
    acc[i] = v;
  }

  __shared__ float red[4][48];
  __shared__ float fin[48];
  if (lane == 0) {
#pragma unroll
    for (int i = 0; i < 48; ++i) red[wv][i] = acc[i];
  }
  __syncthreads();
  if (t < 48) fin[t] = red[0][t] + red[1][t] + red[2][t] + red[3][t];
  __syncthreads();
  if (t < 48) {
    // total prob mass = sum of concept-0 buckets (every state counted once)
    float total = fin[0] + fin[1] + fin[2] + fin[3] + fin[4] + fin[5] + fin[6] + fin[7];
    out[((size_t)(t >> 3) * BROWS + b) * 8 + (t & 7)] = fin[t] / total;
  }
}

// ---------------- launch ----------------
extern "C" void kernel_launch(void* const* d_in, const int* in_sizes, int n_in,
                              void* d_out, int out_size, void* d_ws, size_t ws_size,
                              hipStream_t stream) {
  const float* E    = (const float*)d_in[0];
  const float* W    = (const float*)d_in[1];
  const float* bias = (const float*)d_in[2];
  const int*   vs   = (const int*)d_in[3];
  float* out = (float*)d_out;

  char* ws = (char*)d_ws;
  bf16_t* Eb     = (bf16_t*)ws;                                              // 8 MB
  bf16_t* Wb     = (bf16_t*)(ws + (size_t)BROWS * KD * 2);                   // 16 MB
  bf16_t* expbuf = (bf16_t*)(ws + (size_t)BROWS * KD * 2 + (size_t)NV * KD * 2); // 64 MB

  cvt_kernel<<<2048, 256, 0, stream>>>(E, Eb, BROWS * KD / 4);
  cvt_kernel<<<2048, 256, 0, stream>>>(W, Wb, NV * KD / 4);
  gemm_exp_kernel<<<2048, 256, 0, stream>>>(Eb, Wb, bias, expbuf);
  marginal_kernel<<<BROWS, 256, 0, stream>>>(expbuf, vs, out);
}

// Round 2
// 148.252 us; speedup vs baseline: 1.6888x; 1.6888x over previous
//
#include <hip/hip_runtime.h>
#include <hip/hip_bf16.h>
#include <cstdint>
#include <cstddef>

typedef __bf16 bf16_t;
typedef bf16_t bf16x8 __attribute__((ext_vector_type(8)));
typedef bf16_t bf16x4 __attribute__((ext_vector_type(4)));
typedef float  f32x4  __attribute__((ext_vector_type(4)));
typedef unsigned int u32;

#define BROWS 4096
#define NV    8192
#define KD    1024
#define BM 128
#define BN 128
#define BK 32
#define KSPLIT 16   // marginal kernel K-split (512 states per split)

// async global->LDS, 16B per lane; LDS dst is wave-uniform base + lane*16
#define GLL(gsrc, ldst) \
  __builtin_amdgcn_global_load_lds((const __attribute__((address_space(1))) u32*)(gsrc), \
                                   (__attribute__((address_space(3))) u32*)(ldst), 16, 0, 0)

// ---------------- f32 -> bf16 conversion ----------------
__global__ void cvt_kernel(const float* __restrict__ src, bf16_t* __restrict__ dst, int n4) {
  int idx = blockIdx.x * blockDim.x + threadIdx.x;
  int stride = gridDim.x * blockDim.x;
  for (int i = idx; i < n4; i += stride) {
    float4 v = ((const float4*)src)[i];
    bf16x4 o;
    o[0] = (bf16_t)v.x; o[1] = (bf16_t)v.y; o[2] = (bf16_t)v.z; o[3] = (bf16_t)v.w;
    ((bf16x4*)dst)[i] = o;
  }
}

// ---------------- build S^T: one-hot digit indicator, bf16 [48][NV] ----------------
__global__ void build_st_kernel(const int* __restrict__ vstate, bf16_t* __restrict__ st) {
  int g = blockIdx.x * blockDim.x + threadIdx.x;   // g = bucket*NV + j
  if (g >= 48 * NV) return;
  int bucket = g >> 13;          // /8192
  int j = g & (NV - 1);
  int c = bucket >> 3;           // concept 0..5
  int d = bucket & 7;
  int dig = (vstate[j] >> (15 - 3 * c)) & 7;
  st[g] = (bf16_t)(dig == d ? 1.0f : 0.0f);
}

// ---------------- GEMM: expout = exp(E @ W^T + b), bf16 out ----------------
// m97 structure: 128x128 tile, BK=32, 4 waves (2x2), 4x4 16x16x32 frags/wave,
// linear LDS + global_load_lds width 16, 2 barriers per K-step.
__global__ __launch_bounds__(256)
void gemm_exp_kernel(const bf16_t* __restrict__ A, const bf16_t* __restrict__ B,
                     const float* __restrict__ bias, bf16_t* __restrict__ expout) {
  __shared__ bf16_t sA[BM][BK];   // 8 KB
  __shared__ bf16_t sB[BN][BK];   // 8 KB

  const int t    = threadIdx.x;
  const int lane = t & 63;
  const int wv   = t >> 6;

  // XCD-aware swizzle (2048 blocks % 8 == 0 -> simple form is bijective)
  int bid = blockIdx.x;
  int wg  = (bid & 7) * 256 + (bid >> 3);
  const int mt = wg >> 6;          // 0..31
  const int nt = wg & 63;          // 0..63
  const int row0 = mt * BM;
  const int col0 = nt * BN;

  // staging: thread t, chunk q in {0,1}: row=(q*256+t)/4, kelem=(t&3)*8
  const int srow = t >> 2;
  const int skel = (t & 3) * 8;
  const bf16_t* ap0 = A + (size_t)(row0 + srow) * KD + skel;
  const bf16_t* ap1 = ap0 + (size_t)64 * KD;
  const bf16_t* bp0 = B + (size_t)(col0 + srow) * KD + skel;
  const bf16_t* bp1 = bp0 + (size_t)64 * KD;
  // wave-uniform LDS bases (element offsets; HW adds lane*16B)
  bf16_t* sa0 = &sA[0][0] + (wv * 64) * 8;
  bf16_t* sa1 = &sA[0][0] + (256 + wv * 64) * 8;
  bf16_t* sb0 = &sB[0][0] + (wv * 64) * 8;
  bf16_t* sb1 = &sB[0][0] + (256 + wv * 64) * 8;

  const int wr = (wv >> 1) * 64;   // wave row origin in tile
  const int wc = (wv & 1) * 64;    // wave col origin in tile
  const int fr = lane & 15;
  const int fq = lane >> 4;

  f32x4 acc[4][4] = {};

  for (int k0 = 0; k0 < KD; k0 += BK) {
    GLL(ap0 + k0, sa0);
    GLL(ap1 + k0, sa1);
    GLL(bp0 + k0, sb0);
    GLL(bp1 + k0, sb1);
    __syncthreads();   // drains vmcnt, then barrier: LDS tiles ready

    bf16x8 af[4], bg[4];
#pragma unroll
    for (int i = 0; i < 4; ++i) {
      af[i] = *(const bf16x8*)&sA[wr + i * 16 + fr][fq * 8];
      bg[i] = *(const bf16x8*)&sB[wc + i * 16 + fr][fq * 8];
    }
#pragma unroll
    for (int i = 0; i < 4; ++i)
#pragma unroll
      for (int j = 0; j < 4; ++j)
        acc[i][j] = __builtin_amdgcn_mfma_f32_16x16x32_bf16(af[i], bg[j], acc[i][j], 0, 0, 0);
    __syncthreads();   // all waves done reading before next stage overwrites
  }

  // epilogue: D row=(lane>>4)*4+r, col=lane&15 (measured m89/m91 mapping)
#pragma unroll
  for (int j = 0; j < 4; ++j) {
    const int col = col0 + wc + j * 16 + fr;
    const float bb = bias[col];
#pragma unroll
    for (int i = 0; i < 4; ++i) {
      const int rowb = row0 + wr + i * 16 + fq * 4;
#pragma unroll
      for (int r = 0; r < 4; ++r) {
        // exp(x) = exp2(x * log2(e)); logits bounded ~|4| for this input dist
        float e = exp2f((acc[i][j][r] + bb) * 1.44269504088896340736f);
        expout[(size_t)(rowb + r) * NV + col] = (bf16_t)e;
      }
    }
  }
}

// ---------------- marginals via indicator MFMA GEMM ----------------
// partials[ks][row][bucket] = sum over k in split ks of exp[row][k] * S^T[bucket][k]
__global__ __launch_bounds__(256)
void marginal_mfma_kernel(const bf16_t* __restrict__ expbuf, const bf16_t* __restrict__ st,
                          float* __restrict__ part) {
  __shared__ bf16_t sE[128][BK];  // 8 KB
  __shared__ bf16_t sS[48][BK];   // 3 KB

  const int t    = threadIdx.x;
  const int lane = t & 63;
  const int wv   = t >> 6;

  const int rt = blockIdx.x >> 4;        // row tile 0..31
  const int ks = blockIdx.x & (KSPLIT - 1);
  const int row0 = rt * 128;
  const int kbase = ks * (NV / KSPLIT);  // 512-state range

  const int srow = t >> 2;
  const int skel = (t & 3) * 8;
  const bf16_t* ep0 = expbuf + (size_t)(row0 + srow) * NV + kbase + skel;
  const bf16_t* ep1 = ep0 + (size_t)64 * NV;
  const bf16_t* sp0 = st + (size_t)srow * NV + kbase + skel;   // valid for t<192
  bf16_t* se0 = &sE[0][0] + (wv * 64) * 8;
  bf16_t* se1 = &sE[0][0] + (256 + wv * 64) * 8;
  bf16_t* ss0 = &sS[0][0] + (wv * 64) * 8;

  const int fr = lane & 15;
  const int fq = lane >> 4;

  f32x4 acc[2][3] = {};

  for (int kk = 0; kk < NV / KSPLIT; kk += BK) {
    GLL(ep0 + kk, se0);
    GLL(ep1 + kk, se1);
    if (wv < 3) GLL(sp0 + kk, ss0);
    __syncthreads();

    bf16x8 af[2], bg[3];
#pragma unroll
    for (int m = 0; m < 2; ++m)
      af[m] = *(const bf16x8*)&sE[wv * 32 + m * 16 + fr][fq * 8];
#pragma unroll
    for (int n = 0; n < 3; ++n)
      bg[n] = *(const bf16x8*)&sS[n * 16 + fr][fq * 8];
#pragma unroll
    for (int m = 0; m < 2; ++m)
#pragma unroll
      for (int n = 0; n < 3; ++n)
        acc[m][n] = __builtin_amdgcn_mfma_f32_16x16x32_bf16(af[m], bg[n], acc[m][n], 0, 0, 0);
    __syncthreads();
  }

  // D layout: row = fq*4 + r, col = fr
  float* pbase = part + (size_t)ks * BROWS * 48;
#pragma unroll
  for (int m = 0; m < 2; ++m) {
    const int rowb = row0 + wv * 32 + m * 16 + fq * 4;
#pragma unroll
    for (int n = 0; n < 3; ++n) {
      const int bucket = n * 16 + fr;
#pragma unroll
      for (int r = 0; r < 4; ++r)
        pbase[(size_t)(rowb + r) * 48 + bucket] = acc[m][n][r];
    }
  }
}

// ---------------- reduce partials + normalize ----------------
__global__ __launch_bounds__(64)
void reduce_kernel(const float* __restrict__ part, float* __restrict__ out) {
  const int b = blockIdx.x;
  const int t = threadIdx.x;
  __shared__ float fin[48];
  if (t < 48) {
    float s = 0.f;
#pragma unroll
    for (int ks = 0; ks < KSPLIT; ++ks)
      s += part[((size_t)ks * BROWS + b) * 48 + t];
    fin[t] = s;
  }
  __syncthreads();
  if (t < 48) {
    float total = fin[0] + fin[1] + fin[2] + fin[3] + fin[4] + fin[5] + fin[6] + fin[7];
    out[(size_t)(t >> 3) * BROWS * 8 + (size_t)b * 8 + (t & 7)] = fin[t] / total;
  }
}

// ---------------- launch ----------------
extern "C" void kernel_launch(void* const* d_in, const int* in_sizes, int n_in,
                              void* d_out, int out_size, void* d_ws, size_t ws_size,
                              hipStream_t stream) {
  const float* E    = (const float*)d_in[0];
  const float* W    = (const float*)d_in[1];
  const float* bias = (const float*)d_in[2];
  const int*   vs   = (const int*)d_in[3];
  float* out = (float*)d_out;

  char* ws = (char*)d_ws;
  size_t off = 0;
  bf16_t* Eb     = (bf16_t*)(ws + off); off += (size_t)BROWS * KD * 2;        // 8 MB
  bf16_t* Wb     = (bf16_t*)(ws + off); off += (size_t)NV * KD * 2;           // 16 MB
  bf16_t* expbuf = (bf16_t*)(ws + off); off += (size_t)BROWS * NV * 2;        // 64 MB
  bf16_t* st     = (bf16_t*)(ws + off); off += (size_t)48 * NV * 2;           // 786 KB
  float*  part   = (float*)(ws + off);  off += (size_t)KSPLIT * BROWS * 48 * 4; // 12.6 MB

  build_st_kernel<<<(48 * NV + 255) / 256, 256, 0, stream>>>(vs, st);
  cvt_kernel<<<2048, 256, 0, stream>>>(E, Eb, BROWS * KD / 4);
  cvt_kernel<<<2048, 256, 0, stream>>>(W, Wb, NV * KD / 4);
  gemm_exp_kernel<<<2048, 256, 0, stream>>>(Eb, Wb, bias, expbuf);
  marginal_mfma_kernel<<<32 * KSPLIT, 256, 0, stream>>>(expbuf, st, part);
  reduce_kernel<<<BROWS, 64, 0, stream>>>(part, out);
}

// Round 3
// 127.293 us; speedup vs baseline: 1.9669x; 1.1647x over previous
//
#include <hip/hip_runtime.h>
#include <hip/hip_bf16.h>
#include <cstdint>
#include <cstddef>

typedef __bf16 bf16_t;
typedef bf16_t bf16x8 __attribute__((ext_vector_type(8)));
typedef bf16_t bf16x4 __attribute__((ext_vector_type(4)));
typedef float  f32x4  __attribute__((ext_vector_type(4)));
typedef unsigned int u32;

#define BROWS 4096
#define NV    8192
#define KD    1024
#define KSPLIT 16   // marginal kernel K-split (512 states per split)
#define NT    16    // GEMM K-tiles (1024 / 64)

// async global->LDS, 16B per lane; LDS dst is wave-uniform base + lane*16
#define GLL(gsrc, ldst) \
  __builtin_amdgcn_global_load_lds((const __attribute__((address_space(1))) u32*)(gsrc), \
                                   (__attribute__((address_space(3))) u32*)(ldst), 16, 0, 0)

// ---------------- f32 -> bf16 conversion ----------------
__global__ void cvt_kernel(const float* __restrict__ src, bf16_t* __restrict__ dst, int n4) {
  int idx = blockIdx.x * blockDim.x + threadIdx.x;
  int stride = gridDim.x * blockDim.x;
  for (int i = idx; i < n4; i += stride) {
    float4 v = ((const float4*)src)[i];
    bf16x4 o;
    o[0] = (bf16_t)v.x; o[1] = (bf16_t)v.y; o[2] = (bf16_t)v.z; o[3] = (bf16_t)v.w;
    ((bf16x4*)dst)[i] = o;
  }
}

// ---------------- build S^T: one-hot digit indicator, bf16 [48][NV] ----------------
__global__ void build_st_kernel(const int* __restrict__ vstate, bf16_t* __restrict__ st) {
  int g = blockIdx.x * blockDim.x + threadIdx.x;   // g = bucket*NV + j
  if (g >= 48 * NV) return;
  int bucket = g >> 13;          // /8192
  int j = g & (NV - 1);
  int c = bucket >> 3;           // concept 0..5
  int d = bucket & 7;
  int dig = (vstate[j] >> (15 - 3 * c)) & 7;
  st[g] = (bf16_t)(dig == d ? 1.0f : 0.0f);
}

// ---------------- GEMM: expout = exp(E @ W^T + b), bf16 out ----------------
// 256x256 tile, BK=64, 8 waves (2M x 4N), 128 KiB double-buffered LDS.
// Deep pipeline: tile t+1 staged via global_load_lds while tile t computes;
// counted s_waitcnt vmcnt(8) (never 0 in-loop); raw s_barrier (no compiler
// vmcnt(0) drain); st_16x32 XOR swizzle applied BOTH sides (pre-swizzled
// global source + swizzled ds_read) per rule #21.
__global__ __launch_bounds__(512, 2)
void gemm_exp_kernel(const bf16_t* __restrict__ A, const bf16_t* __restrict__ B,
                     const float* __restrict__ bias, bf16_t* __restrict__ expout) {
  __shared__ __align__(16) char lds[2][65536];   // [dbuf][A 32K | B 32K]

  const int t    = threadIdx.x;
  const int lane = t & 63;
  const int wv   = t >> 6;      // 0..7
  const int wm   = wv >> 2;     // 0..1  (wave row half)
  const int wn   = wv & 3;      // 0..3  (wave col quarter)
  const int fr   = lane & 15;
  const int fq   = lane >> 4;

  // XCD swizzle: 512 blocks, 512 % 8 == 0 -> simple form bijective
  int bid = blockIdx.x;
  int wg  = (bid & 7) * 64 + (bid >> 3);
  const int mt = wg >> 5;       // 0..15
  const int nt = wg & 31;       // 0..31
  const int row0 = mt * 256;
  const int col0 = nt * 256;

  // ---- staging geometry ----
  // Wave wv covers buffer bytes [wv*8192, +8192), GLL j at +j*1024.
  // LDS dest is linear; global source pre-swizzled: logical chunk
  // c = lane ^ (((lane>>5)&1)<<1)  (byte-bit5 <-> bit9 involution on 16B chunks)
  const int c    = lane ^ (((lane >> 5) & 1) << 1);
  const int srow = c >> 3;        // row within the 8-row/1KB group
  const int skel = (c & 7) * 8;   // k-element offset (0..56)
  const bf16_t* gsrc0 = (wv < 4)
      ? A + (size_t)(row0 + wv * 64 + srow) * KD + skel
      : B + (size_t)(col0 + (wv - 4) * 64 + srow) * KD + skel;

  // ---- ds_read geometry (swizzled) ----
  // logical byte in A region: row*128 + kh*64 + fq*16, row = wm*128 + m*16 + fr
  // bit9 of logical == (fr>>2)&1  ->  XOR 32 when fr&4
  const int swz   = (fr & 4) << 3;
  const int lbase = ((fr * 128 + fq * 16) ^ swz);
  const int abase = wm * 16384 + lbase;
  const int bbase = 32768 + wn * 8192 + lbase;

  f32x4 acc[8][4] = {};

  // prologue: stage tile 0, drain, barrier
  {
#pragma unroll
    for (int j = 0; j < 8; ++j)
      GLL(gsrc0 + (size_t)j * 8 * KD, &lds[0][wv * 8192 + j * 1024]);
  }
  asm volatile("s_waitcnt vmcnt(0)" ::: "memory");
  __builtin_amdgcn_s_barrier();
  asm volatile("" ::: "memory");

  int cur = 0;
  for (int kt = 0; kt < NT; ++kt) {
    if (kt + 1 < NT) {
      // issue next tile's loads into the free buffer (freed by prev end-barrier)
#pragma unroll
      for (int j = 0; j < 8; ++j)
        GLL(gsrc0 + (size_t)j * 8 * KD + (kt + 1) * 64, &lds[cur ^ 1][wv * 8192 + j * 1024]);
      // wait only for tile kt's 8 loads (oldest); keep 8 in flight
      asm volatile("s_waitcnt vmcnt(8)" ::: "memory");
    } else {
      asm volatile("s_waitcnt vmcnt(0)" ::: "memory");
    }
    __builtin_amdgcn_s_barrier();          // tile kt resident for all waves
    asm volatile("" ::: "memory");

    const char* bufp = &lds[cur][0];
    bf16x8 bfrag[2][4];
#pragma unroll
    for (int kh = 0; kh < 2; ++kh)
#pragma unroll
      for (int n = 0; n < 4; ++n)
        bfrag[kh][n] = *(const bf16x8*)(bufp + bbase + n * 2048 + kh * 64);

#pragma unroll
    for (int mg = 0; mg < 8; mg += 2) {    // 4 phases of 16 MFMA
      bf16x8 af[2][2];
#pragma unroll
      for (int kh = 0; kh < 2; ++kh)
#pragma unroll
        for (int mi = 0; mi < 2; ++mi)
          af[kh][mi] = *(const bf16x8*)(bufp + abase + (mg + mi) * 2048 + kh * 64);
      __builtin_amdgcn_s_setprio(1);
#pragma unroll
      for (int mi = 0; mi < 2; ++mi)
#pragma unroll
        for (int n = 0; n < 4; ++n)
#pragma unroll
          for (int kh = 0; kh < 2; ++kh)
            acc[mg + mi][n] = __builtin_amdgcn_mfma_f32_16x16x32_bf16(
                af[kh][mi], bfrag[kh][n], acc[mg + mi][n], 0, 0, 0);
      __builtin_amdgcn_s_setprio(0);
    }

    asm volatile("" ::: "memory");
    __builtin_amdgcn_s_barrier();          // all waves done reading lds[cur]
    asm volatile("" ::: "memory");
    cur ^= 1;
  }

  // epilogue: D row = fq*4 + r (within frag), col = fr
#pragma unroll
  for (int n = 0; n < 4; ++n) {
    const int col = col0 + wn * 64 + n * 16 + fr;
    const float bb = bias[col];
#pragma unroll
    for (int m = 0; m < 8; ++m) {
      const int rowb = row0 + wm * 128 + m * 16 + fq * 4;
#pragma unroll
      for (int r = 0; r < 4; ++r) {
        float e = exp2f((acc[m][n][r] + bb) * 1.44269504088896340736f);
        expout[(size_t)(rowb + r) * NV + col] = (bf16_t)e;
      }
    }
  }
}

// ---------------- marginals via indicator MFMA GEMM ----------------
// partials[ks][row][bucket] = sum over k in split ks of exp[row][k] * S^T[bucket][k]
__global__ __launch_bounds__(256)
void marginal_mfma_kernel(const bf16_t* __restrict__ expbuf, const bf16_t* __restrict__ st,
                          float* __restrict__ part) {
  __shared__ bf16_t sE[128][32];  // 8 KB
  __shared__ bf16_t sS[48][32];   // 3 KB

  const int t    = threadIdx.x;
  const int lane = t & 63;
  const int wv   = t >> 6;

  const int rt = blockIdx.x >> 4;        // row tile 0..31
  const int ks = blockIdx.x & (KSPLIT - 1);
  const int row0 = rt * 128;
  const int kbase = ks * (NV / KSPLIT);  // 512-state range

  const int srow = t >> 2;
  const int skel = (t & 3) * 8;
  const bf16_t* ep0 = expbuf + (size_t)(row0 + srow) * NV + kbase + skel;
  const bf16_t* ep1 = ep0 + (size_t)64 * NV;
  const bf16_t* sp0 = st + (size_t)srow * NV + kbase + skel;   // valid for t<192
  bf16_t* se0 = &sE[0][0] + (wv * 64) * 8;
  bf16_t* se1 = &sE[0][0] + (256 + wv * 64) * 8;
  bf16_t* ss0 = &sS[0][0] + (wv * 64) * 8;

  const int fr = lane & 15;
  const int fq = lane >> 4;

  f32x4 acc[2][3] = {};

  for (int kk = 0; kk < NV / KSPLIT; kk += 32) {
    GLL(ep0 + kk, se0);
    GLL(ep1 + kk, se1);
    if (wv < 3) GLL(sp0 + kk, ss0);
    __syncthreads();

    bf16x8 af[2], bg[3];
#pragma unroll
    for (int m = 0; m < 2; ++m)
      af[m] = *(const bf16x8*)&sE[wv * 32 + m * 16 + fr][fq * 8];
#pragma unroll
    for (int n = 0; n < 3; ++n)
      bg[n] = *(const bf16x8*)&sS[n * 16 + fr][fq * 8];
#pragma unroll
    for (int m = 0; m < 2; ++m)
#pragma unroll
      for (int n = 0; n < 3; ++n)
        acc[m][n] = __builtin_amdgcn_mfma_f32_16x16x32_bf16(af[m], bg[n], acc[m][n], 0, 0, 0);
    __syncthreads();
  }

  // D layout: row = fq*4 + r, col = fr
  float* pbase = part + (size_t)ks * BROWS * 48;
#pragma unroll
  for (int m = 0; m < 2; ++m) {
    const int rowb = row0 + wv * 32 + m * 16 + fq * 4;
#pragma unroll
    for (int n = 0; n < 3; ++n) {
      const int bucket = n * 16 + fr;
#pragma unroll
      for (int r = 0; r < 4; ++r)
        pbase[(size_t)(rowb + r) * 48 + bucket] = acc[m][n][r];
    }
  }
}

// ---------------- reduce partials + normalize ----------------
__global__ __launch_bounds__(64)
void reduce_kernel(const float* __restrict__ part, float* __restrict__ out) {
  const int b = blockIdx.x;
  const int t = threadIdx.x;
  __shared__ float fin[48];
  if (t < 48) {
    float s = 0.f;
#pragma unroll
    for (int ks = 0; ks < KSPLIT; ++ks)
      s += part[((size_t)ks * BROWS + b) * 48 + t];
    fin[t] = s;
  }
  __syncthreads();
  if (t < 48) {
    float total = fin[0] + fin[1] + fin[2] + fin[3] + fin[4] + fin[5] + fin[6] + fin[7];
    out[(size_t)(t >> 3) * BROWS * 8 + (size_t)b * 8 + (t & 7)] = fin[t] / total;
  }
}

// ---------------- launch ----------------
extern "C" void kernel_launch(void* const* d_in, const int* in_sizes, int n_in,
                              void* d_out, int out_size, void* d_ws, size_t ws_size,
                              hipStream_t stream) {
  const float* E    = (const float*)d_in[0];
  const float* W    = (const float*)d_in[1];
  const float* bias = (const float*)d_in[2];
  const int*   vs   = (const int*)d_in[3];
  float* out = (float*)d_out;

  char* ws = (char*)d_ws;
  size_t off = 0;
  bf16_t* Eb     = (bf16_t*)(ws + off); off += (size_t)BROWS * KD * 2;        // 8 MB
  bf16_t* Wb     = (bf16_t*)(ws + off); off += (size_t)NV * KD * 2;           // 16 MB
  bf16_t* expbuf = (bf16_t*)(ws + off); off += (size_t)BROWS * NV * 2;        // 64 MB
  bf16_t* st     = (bf16_t*)(ws + off); off += (size_t)48 * NV * 2;           // 786 KB
  float*  part   = (float*)(ws + off);  off += (size_t)KSPLIT * BROWS * 48 * 4; // 12.6 MB

  build_st_kernel<<<(48 * NV + 255) / 256, 256, 0, stream>>>(vs, st);
  cvt_kernel<<<2048, 256, 0, stream>>>(E, Eb, BROWS * KD / 4);
  cvt_kernel<<<2048, 256, 0, stream>>>(W, Wb, NV * KD / 4);
  gemm_exp_kernel<<<512, 512, 0, stream>>>(Eb, Wb, bias, expbuf);
  marginal_mfma_kernel<<<32 * KSPLIT, 256, 0, stream>>>(expbuf, st, part);
  reduce_kernel<<<BROWS, 64, 0, stream>>>(part, out);
}

// Round 4
// 123.658 us; speedup vs baseline: 2.0247x; 1.0294x over previous
//
#include <hip/hip_runtime.h>
#include <hip/hip_bf16.h>
#include <cstdint>
#include <cstddef>

typedef __bf16 bf16_t;
typedef bf16_t bf16x8 __attribute__((ext_vector_type(8)));
typedef bf16_t bf16x4 __attribute__((ext_vector_type(4)));
typedef float  f32x4  __attribute__((ext_vector_type(4)));
typedef unsigned int u32;

#define BROWS 4096
#define NV    8192
#define KD    1024
#define KSPLIT 16   // marginal kernel K-split (512 states per split)
#define NT    16    // GEMM K-tiles (1024 / 64)

// async global->LDS, 16B per lane; LDS dst is wave-uniform base + lane*16
#define GLL(gsrc, ldst) \
  __builtin_amdgcn_global_load_lds((const __attribute__((address_space(1))) u32*)(gsrc), \
                                   (__attribute__((address_space(3))) u32*)(ldst), 16, 0, 0)

// ---------------- f32 -> bf16 conversion ----------------
__global__ void cvt_kernel(const float* __restrict__ src, bf16_t* __restrict__ dst, int n4) {
  int idx = blockIdx.x * blockDim.x + threadIdx.x;
  int stride = gridDim.x * blockDim.x;
  for (int i = idx; i < n4; i += stride) {
    float4 v = ((const float4*)src)[i];
    bf16x4 o;
    o[0] = (bf16_t)v.x; o[1] = (bf16_t)v.y; o[2] = (bf16_t)v.z; o[3] = (bf16_t)v.w;
    ((bf16x4*)dst)[i] = o;
  }
}

// ---------------- build S^T: one-hot digit indicator, bf16 [48][NV] ----------------
__global__ void build_st_kernel(const int* __restrict__ vstate, bf16_t* __restrict__ st) {
  int g = blockIdx.x * blockDim.x + threadIdx.x;   // g = bucket*NV + j
  if (g >= 48 * NV) return;
  int bucket = g >> 13;          // /8192
  int j = g & (NV - 1);
  int c = bucket >> 3;           // concept 0..5
  int d = bucket & 7;
  int dig = (vstate[j] >> (15 - 3 * c)) & 7;
  st[g] = (bf16_t)(dig == d ? 1.0f : 0.0f);
}

// ---------------- GEMM: expout = exp(E @ W^T + b), bf16 out ----------------
// 256x256 tile, BK=64, 8 waves (2M x 4N), 128 KiB double-buffered LDS.
// Pipeline: tile t+1 staged via global_load_lds while tile t computes;
// counted s_waitcnt vmcnt(8) (never 0 in-loop); raw s_barrier.
// LDS swizzle: phys = logical ^ ((row&7)<<4)  (full 3-bit bank-group XOR,
// bits[4:6] ^= row bits[0:2]) applied BOTH sides (rule #21):
//   - stage: linear LDS dest, pre-permuted global source chunk c = l ^ ((l>>3)&7)
//   - read: XOR on full logical addr INCLUDING kh*64 (bit6 participates)
__global__ __launch_bounds__(512, 2)
void gemm_exp_kernel(const bf16_t* __restrict__ A, const bf16_t* __restrict__ B,
                     const float* __restrict__ bias, bf16_t* __restrict__ expout) {
  __shared__ __align__(16) char lds[2][65536];   // [dbuf][A 32K | B 32K]

  const int t    = threadIdx.x;
  const int lane = t & 63;
  const int wv   = t >> 6;      // 0..7
  const int wm   = wv >> 2;     // 0..1  (wave row half)
  const int wn   = wv & 3;      // 0..3  (wave col quarter)
  const int fr   = lane & 15;
  const int fq   = lane >> 4;

  // XCD swizzle: 512 blocks, 512 % 8 == 0 -> simple form bijective
  int bid = blockIdx.x;
  int wg  = (bid & 7) * 64 + (bid >> 3);
  const int mt = wg >> 5;       // 0..15
  const int nt = wg & 31;       // 0..31
  const int row0 = mt * 256;
  const int col0 = nt * 256;

  // ---- staging geometry ----
  // Wave wv covers buffer bytes [wv*8192, +8192), GLL j at +j*1024 (8 rows/chunk).
  // Lane l's 16B lands at physical l*16; inverse swizzle -> fetch logical chunk
  // c = l ^ ((l>>3)&7)  (XOR low 3 chunk bits with row-in-group bits)
  const int c    = lane ^ ((lane >> 3) & 7);
  const int srow = c >> 3;        // row within the 8-row/1KB group
  const int skel = (c & 7) * 8;   // k-element offset (0..56)
  const bf16_t* gsrc0 = (wv < 4)
      ? A + (size_t)(row0 + wv * 64 + srow) * KD + skel
      : B + (size_t)(col0 + (wv - 4) * 64 + srow) * KD + skel;

  // ---- ds_read geometry (swizzled) ----
  // logical byte in region: row*128 + kh*64 + fq*16 (row bits -> addr bits 7..)
  // physical = logical ^ ((fr&7)<<4)   [row&7 == fr&7 for all frag rows]
  const int frs = (fr & 7) << 4;
  int aoff[2], boff[2];
#pragma unroll
  for (int kh = 0; kh < 2; ++kh) {
    const int sw = (fr * 128 + kh * 64 + fq * 16) ^ frs;
    aoff[kh] = wm * 16384 + sw;
    boff[kh] = 32768 + wn * 8192 + sw;
  }

  f32x4 acc[8][4] = {};

  // prologue: stage tile 0, drain, barrier
  {
#pragma unroll
    for (int j = 0; j < 8; ++j)
      GLL(gsrc0 + (size_t)j * 8 * KD, &lds[0][wv * 8192 + j * 1024]);
  }
  asm volatile("s_waitcnt vmcnt(0)" ::: "memory");
  __builtin_amdgcn_s_barrier();
  asm volatile("" ::: "memory");

  int cur = 0;
  for (int kt = 0; kt < NT; ++kt) {
    if (kt + 1 < NT) {
      // issue next tile's loads into the free buffer (freed by prev end-barrier)
#pragma unroll
      for (int j = 0; j < 8; ++j)
        GLL(gsrc0 + (size_t)j * 8 * KD + (kt + 1) * 64, &lds[cur ^ 1][wv * 8192 + j * 1024]);
      // wait only for tile kt's 8 loads (oldest); keep 8 in flight
      asm volatile("s_waitcnt vmcnt(8)" ::: "memory");
    } else {
      asm volatile("s_waitcnt vmcnt(0)" ::: "memory");
    }
    __builtin_amdgcn_s_barrier();          // tile kt resident for all waves
    asm volatile("" ::: "memory");

    const char* bufp = &lds[cur][0];
    bf16x8 bfrag[2][4];
#pragma unroll
    for (int kh = 0; kh < 2; ++kh)
#pragma unroll
      for (int n = 0; n < 4; ++n)
        bfrag[kh][n] = *(const bf16x8*)(bufp + boff[kh] + n * 2048);

#pragma unroll
    for (int mg = 0; mg < 8; mg += 2) {    // 4 phases of 16 MFMA
      bf16x8 af[2][2];
#pragma unroll
      for (int kh = 0; kh < 2; ++kh)
#pragma unroll
        for (int mi = 0; mi < 2; ++mi)
          af[kh][mi] = *(const bf16x8*)(bufp + aoff[kh] + (mg + mi) * 2048);
      __builtin_amdgcn_s_setprio(1);
#pragma unroll
      for (int mi = 0; mi < 2; ++mi)
#pragma unroll
        for (int n = 0; n < 4; ++n)
#pragma unroll
          for (int kh = 0; kh < 2; ++kh)
            acc[mg + mi][n] = __builtin_amdgcn_mfma_f32_16x16x32_bf16(
                af[kh][mi], bfrag[kh][n], acc[mg + mi][n], 0, 0, 0);
      __builtin_amdgcn_s_setprio(0);
    }

    asm volatile("" ::: "memory");
    __builtin_amdgcn_s_barrier();          // all waves done reading lds[cur]
    asm volatile("" ::: "memory");
    cur ^= 1;
  }

  // epilogue: D row = fq*4 + r (within frag), col = fr
#pragma unroll
  for (int n = 0; n < 4; ++n) {
    const int col = col0 + wn * 64 + n * 16 + fr;
    const float bb = bias[col];
#pragma unroll
    for (int m = 0; m < 8; ++m) {
      const int rowb = row0 + wm * 128 + m * 16 + fq * 4;
#pragma unroll
      for (int r = 0; r < 4; ++r) {
        float e = exp2f((acc[m][n][r] + bb) * 1.44269504088896340736f);
        expout[(size_t)(rowb + r) * NV + col] = (bf16_t)e;
      }
    }
  }
}

// ---------------- marginals via indicator MFMA GEMM ----------------
// partials[ks][row][bucket] = sum over k in split ks of exp[row][k] * S^T[bucket][k]
__global__ __launch_bounds__(256)
void marginal_mfma_kernel(const bf16_t* __restrict__ expbuf, const bf16_t* __restrict__ st,
                          float* __restrict__ part) {
  __shared__ bf16_t sE[128][32];  // 8 KB
  __shared__ bf16_t sS[48][32];   // 3 KB

  const int t    = threadIdx.x;
  const int lane = t & 63;
  const int wv   = t >> 6;

  const int rt = blockIdx.x >> 4;        // row tile 0..31
  const int ks = blockIdx.x & (KSPLIT - 1);
  const int row0 = rt * 128;
  const int kbase = ks * (NV / KSPLIT);  // 512-state range

  const int srow = t >> 2;
  const int skel = (t & 3) * 8;
  const bf16_t* ep0 = expbuf + (size_t)(row0 + srow) * NV + kbase + skel;
  const bf16_t* ep1 = ep0 + (size_t)64 * NV;
  const bf16_t* sp0 = st + (size_t)srow * NV + kbase + skel;   // valid for t<192
  bf16_t* se0 = &sE[0][0] + (wv * 64) * 8;
  bf16_t* se1 = &sE[0][0] + (256 + wv * 64) * 8;
  bf16_t* ss0 = &sS[0][0] + (wv * 64) * 8;

  const int fr = lane & 15;
  const int fq = lane >> 4;

  f32x4 acc[2][3] = {};

  for (int kk = 0; kk < NV / KSPLIT; kk += 32) {
    GLL(ep0 + kk, se0);
    GLL(ep1 + kk, se1);
    if (wv < 3) GLL(sp0 + kk, ss0);
    __syncthreads();

    bf16x8 af[2], bg[3];
#pragma unroll
    for (int m = 0; m < 2; ++m)
      af[m] = *(const bf16x8*)&sE[wv * 32 + m * 16 + fr][fq * 8];
#pragma unroll
    for (int n = 0; n < 3; ++n)
      bg[n] = *(const bf16x8*)&sS[n * 16 + fr][fq * 8];
#pragma unroll
    for (int m = 0; m < 2; ++m)
#pragma unroll
      for (int n = 0; n < 3; ++n)
        acc[m][n] = __builtin_amdgcn_mfma_f32_16x16x32_bf16(af[m], bg[n], acc[m][n], 0, 0, 0);
    __syncthreads();
  }

  // D layout: row = fq*4 + r, col = fr
  float* pbase = part + (size_t)ks * BROWS * 48;
#pragma unroll
  for (int m = 0; m < 2; ++m) {
    const int rowb = row0 + wv * 32 + m * 16 + fq * 4;
#pragma unroll
    for (int n = 0; n < 3; ++n) {
      const int bucket = n * 16 + fr;
#pragma unroll
      for (int r = 0; r < 4; ++r)
        pbase[(size_t)(rowb + r) * 48 + bucket] = acc[m][n][r];
    }
  }
}

// ---------------- reduce partials + normalize ----------------
__global__ __launch_bounds__(64)
void reduce_kernel(const float* __restrict__ part, float* __restrict__ out) {
  const int b = blockIdx.x;
  const int t = threadIdx.x;
  __shared__ float fin[48];
  if (t < 48) {
    float s = 0.f;
#pragma unroll
    for (int ks = 0; ks < KSPLIT; ++ks)
      s += part[((size_t)ks * BROWS + b) * 48 + t];
    fin[t] = s;
  }
  __syncthreads();
  if (t < 48) {
    float total = fin[0] + fin[1] + fin[2] + fin[3] + fin[4] + fin[5] + fin[6] + fin[7];
    out[(size_t)(t >> 3) * BROWS * 8 + (size_t)b * 8 + (t & 7)] = fin[t] / total;
  }
}

// ---------------- launch ----------------
extern "C" void kernel_launch(void* const* d_in, const int* in_sizes, int n_in,
                              void* d_out, int out_size, void* d_ws, size_t ws_size,
                              hipStream_t stream) {
  const float* E    = (const float*)d_in[0];
  const float* W    = (const float*)d_in[1];
  const float* bias = (const float*)d_in[2];
  const int*   vs   = (const int*)d_in[3];
  float* out = (float*)d_out;

  char* ws = (char*)d_ws;
  size_t off = 0;
  bf16_t* Eb     = (bf16_t*)(ws + off); off += (size_t)BROWS * KD * 2;        // 8 MB
  bf16_t* Wb     = (bf16_t*)(ws + off); off += (size_t)NV * KD * 2;           // 16 MB
  bf16_t* expbuf = (bf16_t*)(ws + off); off += (size_t)BROWS * NV * 2;        // 64 MB
  bf16_t* st     = (bf16_t*)(ws + off); off += (size_t)48 * NV * 2;           // 786 KB
  float*  part   = (float*)(ws + off);  off += (size_t)KSPLIT * BROWS * 48 * 4; // 12.6 MB

  build_st_kernel<<<(48 * NV + 255) / 256, 256, 0, stream>>>(vs, st);
  cvt_kernel<<<2048, 256, 0, stream>>>(E, Eb, BROWS * KD / 4);
  cvt_kernel<<<2048, 256, 0, stream>>>(W, Wb, NV * KD / 4);
  gemm_exp_kernel<<<512, 512, 0, stream>>>(Eb, Wb, bias, expbuf);
  marginal_mfma_kernel<<<32 * KSPLIT, 256, 0, stream>>>(expbuf, st, part);
  reduce_kernel<<<BROWS, 64, 0, stream>>>(part, out);
}

// Round 5
// 122.378 us; speedup vs baseline: 2.0459x; 1.0105x over previous
//
#include <hip/hip_runtime.h>
#include <hip/hip_bf16.h>
#include <cstdint>
#include <cstddef>

typedef __bf16 bf16_t;
typedef bf16_t bf16x8 __attribute__((ext_vector_type(8)));
typedef bf16_t bf16x4 __attribute__((ext_vector_type(4)));
typedef float  f32x4  __attribute__((ext_vector_type(4)));
typedef unsigned int u32;

#define BROWS 4096
#define NV    8192
#define KD    1024
#define KSPLIT 16   // marginal kernel K-split (512 states per split)
#define NT    16    // GEMM K-tiles (1024 / 64)

// async global->LDS, 16B per lane; LDS dst is wave-uniform base + lane*16
#define GLL(gsrc, ldst) \
  __builtin_amdgcn_global_load_lds((const __attribute__((address_space(1))) u32*)(gsrc), \
                                   (__attribute__((address_space(3))) u32*)(ldst), 16, 0, 0)
#define FENCE asm volatile("" ::: "memory")

// ---------------- f32 -> bf16 conversion ----------------
__global__ void cvt_kernel(const float* __restrict__ src, bf16_t* __restrict__ dst, int n4) {
  int idx = blockIdx.x * blockDim.x + threadIdx.x;
  int stride = gridDim.x * blockDim.x;
  for (int i = idx; i < n4; i += stride) {
    float4 v = ((const float4*)src)[i];
    bf16x4 o;
    o[0] = (bf16_t)v.x; o[1] = (bf16_t)v.y; o[2] = (bf16_t)v.z; o[3] = (bf16_t)v.w;
    ((bf16x4*)dst)[i] = o;
  }
}

// ---------------- build S^T: one-hot digit indicator, bf16 [48][NV] ----------------
__global__ void build_st_kernel(const int* __restrict__ vstate, bf16_t* __restrict__ st) {
  int g = blockIdx.x * blockDim.x + threadIdx.x;   // g = bucket*NV + j
  if (g >= 48 * NV) return;
  int bucket = g >> 13;          // /8192
  int j = g & (NV - 1);
  int c = bucket >> 3;           // concept 0..5
  int d = bucket & 7;
  int dig = (vstate[j] >> (15 - 3 * c)) & 7;
  st[g] = (bf16_t)(dig == d ? 1.0f : 0.0f);
}

// ---------------- GEMM: expout = exp(E @ W^T + b), bf16 out ----------------
// 256x256 tile, BK=64, 8 waves (2M x 4N), 128 KiB double-buffered LDS.
// 8-phase schedule (4 phases per K-tile, 2 K-tiles per conceptual iter):
// half-tiles split by K-half: {A-kh0, B-kh0, A-kh1, B-kh1} x 16 KB.
// Each phase: {ds_read 4-8 x b128, stage 1 half-tile (2 GLL), barrier,
// setprio(1), 16 MFMA, setprio(0), [vmcnt(4) at P1/P3], barrier}.
// Counted vmcnt(4) twice per K-tile, never 0 in-loop (T3+T4); swizzle (T2)
// for 64B-row layout: phys = logical ^ ((row&6)<<3), source pre-permuted
// kslot = (l&3)^((l>>3)&3) (rule #21, both-sides involution).
__global__ __launch_bounds__(512, 2)
void gemm_exp_kernel(const bf16_t* __restrict__ A, const bf16_t* __restrict__ B,
                     const float* __restrict__ bias, bf16_t* __restrict__ expout) {
  __shared__ __align__(16) char lds[2][65536];
  // region byte offsets within one 64 KB buffer
  #define AKH0 0
  #define AKH1 16384
  #define BKH0 32768
  #define BKH1 49152

  const int t    = threadIdx.x;
  const int lane = t & 63;
  const int wv   = t >> 6;      // 0..7
  const int wm   = wv >> 2;     // 0..1  (wave row half)
  const int wn   = wv & 3;      // 0..3  (wave col quarter)
  const int fr   = lane & 15;
  const int fq   = lane >> 4;

  // XCD swizzle: 512 blocks, 512 % 8 == 0 -> simple form bijective
  int bid = blockIdx.x;
  int wg  = (bid & 7) * 64 + (bid >> 3);
  const int mt = wg >> 5;       // 0..15
  const int nt = wg & 31;       // 0..31
  const int row0 = mt * 256;
  const int col0 = nt * 256;

  // ---- staging geometry ----
  // Half-tile = 256 rows x 32 k (16 KB) = 16 chunks of 1 KB (16 rows each).
  // Wave wv stages chunks {2wv, 2wv+1}. Lane l: row = chunk*16 + (l>>2),
  // phys k-slot l&3; inverse swizzle -> fetch logical k-slot (l&3)^((l>>3)&3).
  const int srow = lane >> 2;
  const int skel = ((lane & 3) ^ ((lane >> 3) & 3)) * 8;
  const bf16_t* aptr = A + (size_t)(row0 + wv * 32 + srow) * KD + skel;
  const bf16_t* bptr = B + (size_t)(col0 + wv * 32 + srow) * KD + skel;
  const int dchunk = (wv * 2) * 1024;    // wave's chunk-pair base in each region

  // ---- ds_read geometry (swizzled) ----
  // within a region: logical = row*64 + fq*16; phys = logical ^ ((row&6)<<3)
  // (row&6 == fr&6 for all fragment rows; mg*1024 / n*1024 don't touch bits 4-6)
  const int xsw = (fr & 6) << 3;
  const int base_a = (((wm * 128 + fr) * 64 + fq * 16) ^ xsw);
  const int base_b = 32768 + (((wn * 64 + fr) * 64 + fq * 16) ^ xsw);

  f32x4 acc[8][4] = {};

  // ---- prologue: stage kt0 halves in order Akh0, Bkh0, Akh1, Bkh1
  GLL(aptr, &lds[0][AKH0 + dchunk]);
  GLL(aptr + 16 * KD, &lds[0][AKH0 + dchunk + 1024]);
  GLL(bptr, &lds[0][BKH0 + dchunk]);
  GLL(bptr + 16 * KD, &lds[0][BKH0 + dchunk + 1024]);
  GLL(aptr + 32, &lds[0][AKH1 + dchunk]);
  GLL(aptr + 32 + 16 * KD, &lds[0][AKH1 + dchunk + 1024]);
  GLL(bptr + 32, &lds[0][BKH1 + dchunk]);
  GLL(bptr + 32 + 16 * KD, &lds[0][BKH1 + dchunk + 1024]);
  asm volatile("s_waitcnt vmcnt(4)" ::: "memory");   // Akh0,Bkh0 resident
  __builtin_amdgcn_s_barrier();
  FENCE;

  int cur = 0;
  for (int kt = 0; kt < NT; ++kt) {
    const char* bufp = lds[cur];
    char* nbuf = lds[cur ^ 1];
    const bf16_t* anext = aptr + (kt + 1) * 64;
    const bf16_t* bnext = bptr + (kt + 1) * 64;
    const bool pf = (kt + 1 < NT);

    bf16x8 bfrag[4], af[4];

    // ===== P0: kh0, mg 0-3 (8 ds_read; stage next Akh0) =====
#pragma unroll
    for (int n = 0; n < 4; ++n)
      bfrag[n] = *(const bf16x8*)(bufp + base_b + n * 1024);
#pragma unroll
    for (int mi = 0; mi < 4; ++mi)
      af[mi] = *(const bf16x8*)(bufp + base_a + mi * 1024);
    if (pf) {
      GLL(anext, &nbuf[AKH0 + dchunk]);
      GLL(anext + 16 * KD, &nbuf[AKH0 + dchunk + 1024]);
    }
    FENCE; __builtin_amdgcn_s_barrier(); FENCE;
    __builtin_amdgcn_s_setprio(1);
#pragma unroll
    for (int mi = 0; mi < 4; ++mi)
#pragma unroll
      for (int n = 0; n < 4; ++n)
        acc[mi][n] = __builtin_amdgcn_mfma_f32_16x16x32_bf16(af[mi], bfrag[n], acc[mi][n], 0, 0, 0);
    __builtin_amdgcn_s_setprio(0);
    FENCE; __builtin_amdgcn_s_barrier(); FENCE;

    // ===== P1: kh0, mg 4-7 (4 ds_read; stage next Bkh0; gate for kh1) =====
#pragma unroll
    for (int mi = 0; mi < 4; ++mi)
      af[mi] = *(const bf16x8*)(bufp + base_a + (4 + mi) * 1024);
    if (pf) {
      GLL(bnext, &nbuf[BKH0 + dchunk]);
      GLL(bnext + 16 * KD, &nbuf[BKH0 + dchunk + 1024]);
    }
    FENCE; __builtin_amdgcn_s_barrier(); FENCE;
    __builtin_amdgcn_s_setprio(1);
#pragma unroll
    for (int mi = 0; mi < 4; ++mi)
#pragma unroll
      for (int n = 0; n < 4; ++n)
        acc[4 + mi][n] = __builtin_amdgcn_mfma_f32_16x16x32_bf16(af[mi], bfrag[n], acc[4 + mi][n], 0, 0, 0);
    __builtin_amdgcn_s_setprio(0);
    // gate: this kt's Akh1/Bkh1 must be resident for P2 (keep next kt's 4 loads in flight)
    if (pf) asm volatile("s_waitcnt vmcnt(4)" ::: "memory");
    else    asm volatile("s_waitcnt vmcnt(0)" ::: "memory");
    FENCE; __builtin_amdgcn_s_barrier(); FENCE;

    // ===== P2: kh1, mg 0-3 (8 ds_read; stage next Akh1) =====
#pragma unroll
    for (int n = 0; n < 4; ++n)
      bfrag[n] = *(const bf16x8*)(bufp + base_b + 16384 + n * 1024);
#pragma unroll
    for (int mi = 0; mi < 4; ++mi)
      af[mi] = *(const bf16x8*)(bufp + base_a + 16384 + mi * 1024);
    if (pf) {
      GLL(anext + 32, &nbuf[AKH1 + dchunk]);
      GLL(anext + 32 + 16 * KD, &nbuf[AKH1 + dchunk + 1024]);
    }
    FENCE; __builtin_amdgcn_s_barrier(); FENCE;
    __builtin_amdgcn_s_setprio(1);
#pragma unroll
    for (int mi = 0; mi < 4; ++mi)
#pragma unroll
      for (int n = 0; n < 4; ++n)
        acc[mi][n] = __builtin_amdgcn_mfma_f32_16x16x32_bf16(af[mi], bfrag[n], acc[mi][n], 0, 0, 0);
    __builtin_amdgcn_s_setprio(0);
    FENCE; __builtin_amdgcn_s_barrier(); FENCE;

    // ===== P3: kh1, mg 4-7 (4 ds_read; stage next Bkh1; gate for next P0) =====
#pragma unroll
    for (int mi = 0; mi < 4; ++mi)
      af[mi] = *(const bf16x8*)(bufp + base_a + 16384 + (4 + mi) * 1024);
    if (pf) {
      GLL(bnext + 32, &nbuf[BKH1 + dchunk]);
      GLL(bnext + 32 + 16 * KD, &nbuf[BKH1 + dchunk + 1024]);
    }
    FENCE; __builtin_amdgcn_s_barrier(); FENCE;
    __builtin_amdgcn_s_setprio(1);
#pragma unroll
    for (int mi = 0; mi < 4; ++mi)
#pragma unroll
      for (int n = 0; n < 4; ++n)
        acc[4 + mi][n] = __builtin_amdgcn_mfma_f32_16x16x32_bf16(af[mi], bfrag[n], acc[4 + mi][n], 0, 0, 0);
    __builtin_amdgcn_s_setprio(0);
    // gate: next kt's Akh0/Bkh0 resident for its P0 (keep its kh1 loads in flight)
    if (pf) asm volatile("s_waitcnt vmcnt(4)" ::: "memory");
    FENCE; __builtin_amdgcn_s_barrier(); FENCE;

    cur ^= 1;
  }

  // epilogue: D row = fq*4 + r (within frag), col = fr
#pragma unroll
  for (int n = 0; n < 4; ++n) {
    const int col = col0 + wn * 64 + n * 16 + fr;
    const float bb = bias[col];
#pragma unroll
    for (int m = 0; m < 8; ++m) {
      const int rowb = row0 + wm * 128 + m * 16 + fq * 4;
#pragma unroll
      for (int r = 0; r < 4; ++r) {
        float e = exp2f((acc[m][n][r] + bb) * 1.44269504088896340736f);
        expout[(size_t)(rowb + r) * NV + col] = (bf16_t)e;
      }
    }
  }
}

// ---------------- marginals via indicator MFMA GEMM ----------------
// partials[ks][row][bucket] = sum over k in split ks of exp[row][k] * S^T[bucket][k]
__global__ __launch_bounds__(256)
void marginal_mfma_kernel(const bf16_t* __restrict__ expbuf, const bf16_t* __restrict__ st,
                          float* __restrict__ part) {
  __shared__ bf16_t sE[128][32];  // 8 KB
  __shared__ bf16_t sS[48][32];   // 3 KB

  const int t    = threadIdx.x;
  const int lane = t & 63;
  const int wv   = t >> 6;

  const int rt = blockIdx.x >> 4;        // row tile 0..31
  const int ks = blockIdx.x & (KSPLIT - 1);
  const int row0 = rt * 128;
  const int kbase = ks * (NV / KSPLIT);  // 512-state range

  const int srow = t >> 2;
  const int skel = (t & 3) * 8;
  const bf16_t* ep0 = expbuf + (size_t)(row0 + srow) * NV + kbase + skel;
  const bf16_t* ep1 = ep0 + (size_t)64 * NV;
  const bf16_t* sp0 = st + (size_t)srow * NV + kbase + skel;   // valid for t<192
  bf16_t* se0 = &sE[0][0] + (wv * 64) * 8;
  bf16_t* se1 = &sE[0][0] + (256 + wv * 64) * 8;
  bf16_t* ss0 = &sS[0][0] + (wv * 64) * 8;

  const int fr = lane & 15;
  const int fq = lane >> 4;

  f32x4 acc[2][3] = {};

  for (int kk = 0; kk < NV / KSPLIT; kk += 32) {
    GLL(ep0 + kk, se0);
    GLL(ep1 + kk, se1);
    if (wv < 3) GLL(sp0 + kk, ss0);
    __syncthreads();

    bf16x8 af[2], bg[3];
#pragma unroll
    for (int m = 0; m < 2; ++m)
      af[m] = *(const bf16x8*)&sE[wv * 32 + m * 16 + fr][fq * 8];
#pragma unroll
    for (int n = 0; n < 3; ++n)
      bg[n] = *(const bf16x8*)&sS[n * 16 + fr][fq * 8];
#pragma unroll
    for (int m = 0; m < 2; ++m)
#pragma unroll
      for (int n = 0; n < 3; ++n)
        acc[m][n] = __builtin_amdgcn_mfma_f32_16x16x32_bf16(af[m], bg[n], acc[m][n], 0, 0, 0);
    __syncthreads();
  }

  // D layout: row = fq*4 + r, col = fr
  float* pbase = part + (size_t)ks * BROWS * 48;
#pragma unroll
  for (int m = 0; m < 2; ++m) {
    const int rowb = row0 + wv * 32 + m * 16 + fq * 4;
#pragma unroll
    for (int n = 0; n < 3; ++n) {
      const int bucket = n * 16 + fr;
#pragma unroll
      for (int r = 0; r < 4; ++r)
        pbase[(size_t)(rowb + r) * 48 + bucket] = acc[m][n][r];
    }
  }
}

// ---------------- reduce partials + normalize ----------------
__global__ __launch_bounds__(64)
void reduce_kernel(const float* __restrict__ part, float* __restrict__ out) {
  const int b = blockIdx.x;
  const int t = threadIdx.x;
  __shared__ float fin[48];
  if (t < 48) {
    float s = 0.f;
#pragma unroll
    for (int ks = 0; ks < KSPLIT; ++ks)
      s += part[((size_t)ks * BROWS + b) * 48 + t];
    fin[t] = s;
  }
  __syncthreads();
  if (t < 48) {
    float total = fin[0] + fin[1] + fin[2] + fin[3] + fin[4] + fin[5] + fin[6] + fin[7];
    out[(size_t)(t >> 3) * BROWS * 8 + (size_t)b * 8 + (t & 7)] = fin[t] / total;
  }
}

// ---------------- launch ----------------
extern "C" void kernel_launch(void* const* d_in, const int* in_sizes, int n_in,
                              void* d_out, int out_size, void* d_ws, size_t ws_size,
                              hipStream_t stream) {
  const float* E    = (const float*)d_in[0];
  const float* W    = (const float*)d_in[1];
  const float* bias = (const float*)d_in[2];
  const int*   vs   = (const int*)d_in[3];
  float* out = (float*)d_out;

  char* ws = (char*)d_ws;
  size_t off = 0;
  bf16_t* Eb     = (bf16_t*)(ws + off); off += (size_t)BROWS * KD * 2;        // 8 MB
  bf16_t* Wb     = (bf16_t*)(ws + off); off += (size_t)NV * KD * 2;           // 16 MB
  bf16_t* expbuf = (bf16_t*)(ws + off); off += (size_t)BROWS * NV * 2;        // 64 MB
  bf16_t* st     = (bf16_t*)(ws + off); off += (size_t)48 * NV * 2;           // 786 KB
  float*  part   = (float*)(ws + off);  off += (size_t)KSPLIT * BROWS * 48 * 4; // 12.6 MB

  build_st_kernel<<<(48 * NV + 255) / 256, 256, 0, stream>>>(vs, st);
  cvt_kernel<<<2048, 256, 0, stream>>>(E, Eb, BROWS * KD / 4);
  cvt_kernel<<<2048, 256, 0, stream>>>(W, Wb, NV * KD / 4);
  gemm_exp_kernel<<<512, 512, 0, stream>>>(Eb, Wb, bias, expbuf);
  marginal_mfma_kernel<<<32 * KSPLIT, 256, 0, stream>>>(expbuf, st, part);
  reduce_kernel<<<BROWS, 64, 0, stream>>>(part, out);
}

// Round 6
// 119.571 us; speedup vs baseline: 2.0939x; 1.0235x over previous
//
#include <hip/hip_runtime.h>
#include <hip/hip_bf16.h>
#include <cstdint>
#include <cstddef>

typedef __bf16 bf16_t;
typedef bf16_t bf16x8 __attribute__((ext_vector_type(8)));
typedef bf16_t bf16x4 __attribute__((ext_vector_type(4)));
typedef float  f32x4  __attribute__((ext_vector_type(4)));
typedef unsigned int u32;

#define BROWS 4096
#define NV    8192
#define KD    1024
#define KSPLIT 16   // marginal kernel K-split (512 states per split)
#define NT    16    // GEMM K-tiles (1024 / 64)

// async global->LDS, 16B per lane; LDS dst is wave-uniform base + lane*16
#define GLL(gsrc, ldst) \
  __builtin_amdgcn_global_load_lds((const __attribute__((address_space(1))) u32*)(gsrc), \
                                   (__attribute__((address_space(3))) u32*)(ldst), 16, 0, 0)
#define FENCE asm volatile("" ::: "memory")

// ---------------- f32 -> bf16 conversion ----------------
__global__ void cvt_kernel(const float* __restrict__ src, bf16_t* __restrict__ dst, int n4) {
  int idx = blockIdx.x * blockDim.x + threadIdx.x;
  int stride = gridDim.x * blockDim.x;
  for (int i = idx; i < n4; i += stride) {
    float4 v = ((const float4*)src)[i];
    bf16x4 o;
    o[0] = (bf16_t)v.x; o[1] = (bf16_t)v.y; o[2] = (bf16_t)v.z; o[3] = (bf16_t)v.w;
    ((bf16x4*)dst)[i] = o;
  }
}

// ---------------- build S^T: one-hot digit indicator, bf16 [48][NV] ----------------
__global__ void build_st_kernel(const int* __restrict__ vstate, bf16_t* __restrict__ st) {
  int g = blockIdx.x * blockDim.x + threadIdx.x;   // g = bucket*NV + j
  if (g >= 48 * NV) return;
  int bucket = g >> 13;          // /8192
  int j = g & (NV - 1);
  int c = bucket >> 3;           // concept 0..5
  int d = bucket & 7;
  int dig = (vstate[j] >> (15 - 3 * c)) & 7;
  st[g] = (bf16_t)(dig == d ? 1.0f : 0.0f);
}

// ---------------- GEMM: expout = exp(E @ W^T + b), bf16 out ----------------
// 256x256 tile, BK=64, 8 waves (2M x 4N), 128 KiB double-buffered LDS.
// ONE barrier per K-tile; in-window software pipeline:
//   [read 12 frags kh0 | issue 8 GLL next tile | read 12 frags kh1]
//   -> MFMA kh0 (kh1 reads in flight) -> MFMA kh1 -> vmcnt(0, own stages)
//   -> s_barrier.
// Compiler inserts counted lgkmcnt for frag uses (m97-verified behavior).
// Swizzle (T2) unchanged from R4: 64B-row regions, phys = logical ^ ((row&6)<<3),
// source pre-permuted kslot = (l&3)^((l>>3)&3) (both-sides involution, rule #21).
__global__ __launch_bounds__(512, 2)
void gemm_exp_kernel(const bf16_t* __restrict__ A, const bf16_t* __restrict__ B,
                     const float* __restrict__ bias, bf16_t* __restrict__ expout) {
  __shared__ __align__(16) char lds[2][65536];
  // region byte offsets within one 64 KB buffer
  #define AKH0 0
  #define AKH1 16384
  #define BKH0 32768
  #define BKH1 49152

  const int t    = threadIdx.x;
  const int lane = t & 63;
  const int wv   = t >> 6;      // 0..7
  const int wm   = wv >> 2;     // 0..1  (wave row half)
  const int wn   = wv & 3;      // 0..3  (wave col quarter)
  const int fr   = lane & 15;
  const int fq   = lane >> 4;

  // XCD swizzle: 512 blocks, 512 % 8 == 0 -> simple form bijective
  int bid = blockIdx.x;
  int wg  = (bid & 7) * 64 + (bid >> 3);
  const int mt = wg >> 5;       // 0..15
  const int nt = wg & 31;       // 0..31
  const int row0 = mt * 256;
  const int col0 = nt * 256;

  // ---- staging geometry ----
  // Half-tile = 256 rows x 32 k (16 KB) = 16 chunks of 1 KB (16 rows each).
  // Wave wv stages chunks {2wv, 2wv+1}. Lane l: row = chunk*16 + (l>>2),
  // phys k-slot l&3; inverse swizzle -> fetch logical k-slot (l&3)^((l>>3)&3).
  const int srow = lane >> 2;
  const int skel = ((lane & 3) ^ ((lane >> 3) & 3)) * 8;
  const bf16_t* aptr = A + (size_t)(row0 + wv * 32 + srow) * KD + skel;
  const bf16_t* bptr = B + (size_t)(col0 + wv * 32 + srow) * KD + skel;
  const int dchunk = (wv * 2) * 1024;    // wave's chunk-pair base in each region

  // ---- ds_read geometry (swizzled) ----
  // within a region: logical = row*64 + fq*16; phys = logical ^ ((row&6)<<3)
  // (row&6 == fr&6 for all fragment rows; mg*1024 / n*1024 don't touch bits 4-6)
  const int xsw = (fr & 6) << 3;
  const int base_a = (((wm * 128 + fr) * 64 + fq * 16) ^ xsw);
  const int base_b = 32768 + (((wn * 64 + fr) * 64 + fq * 16) ^ xsw);

  f32x4 acc[8][4] = {};

  // ---- prologue: stage kt0, drain, barrier
  GLL(aptr, &lds[0][AKH0 + dchunk]);
  GLL(aptr + 16 * KD, &lds[0][AKH0 + dchunk + 1024]);
  GLL(bptr, &lds[0][BKH0 + dchunk]);
  GLL(bptr + 16 * KD, &lds[0][BKH0 + dchunk + 1024]);
  GLL(aptr + 32, &lds[0][AKH1 + dchunk]);
  GLL(aptr + 32 + 16 * KD, &lds[0][AKH1 + dchunk + 1024]);
  GLL(bptr + 32, &lds[0][BKH1 + dchunk]);
  GLL(bptr + 32 + 16 * KD, &lds[0][BKH1 + dchunk + 1024]);
  asm volatile("s_waitcnt vmcnt(0)" ::: "memory");
  __builtin_amdgcn_s_barrier();
  FENCE;

  int cur = 0;
  for (int kt = 0; kt < NT; ++kt) {
    const char* bufp = lds[cur];
    char* nbuf = lds[cur ^ 1];
    const bool pf = (kt + 1 < NT);

    bf16x8 a0[8], b0[4], a1[8], b1[4];

    // kh0 fragment reads (12 x ds_read_b128)
#pragma unroll
    for (int n = 0; n < 4; ++n)
      b0[n] = *(const bf16x8*)(bufp + base_b + n * 1024);
#pragma unroll
    for (int m = 0; m < 8; ++m)
      a0[m] = *(const bf16x8*)(bufp + base_a + m * 1024);

    // stage next K-tile into the other buffer (8 x global_load_lds)
    if (pf) {
      const bf16_t* an = aptr + (kt + 1) * 64;
      const bf16_t* bn = bptr + (kt + 1) * 64;
      GLL(an, &nbuf[AKH0 + dchunk]);
      GLL(an + 16 * KD, &nbuf[AKH0 + dchunk + 1024]);
      GLL(bn, &nbuf[BKH0 + dchunk]);
      GLL(bn + 16 * KD, &nbuf[BKH0 + dchunk + 1024]);
      GLL(an + 32, &nbuf[AKH1 + dchunk]);
      GLL(an + 32 + 16 * KD, &nbuf[AKH1 + dchunk + 1024]);
      GLL(bn + 32, &nbuf[BKH1 + dchunk]);
      GLL(bn + 32 + 16 * KD, &nbuf[BKH1 + dchunk + 1024]);
    }

    // kh1 fragment reads (12 x ds_read_b128) — fly during kh0 MFMA
#pragma unroll
    for (int n = 0; n < 4; ++n)
      b1[n] = *(const bf16x8*)(bufp + base_b + 16384 + n * 1024);
#pragma unroll
    for (int m = 0; m < 8; ++m)
      a1[m] = *(const bf16x8*)(bufp + base_a + 16384 + m * 1024);

    __builtin_amdgcn_s_setprio(1);
#pragma unroll
    for (int m = 0; m < 8; ++m)
#pragma unroll
      for (int n = 0; n < 4; ++n)
        acc[m][n] = __builtin_amdgcn_mfma_f32_16x16x32_bf16(a0[m], b0[n], acc[m][n], 0, 0, 0);
#pragma unroll
    for (int m = 0; m < 8; ++m)
#pragma unroll
      for (int n = 0; n < 4; ++n)
        acc[m][n] = __builtin_amdgcn_mfma_f32_16x16x32_bf16(a1[m], b1[n], acc[m][n], 0, 0, 0);
    __builtin_amdgcn_s_setprio(0);

    // own stages done (issued ~a full K-tile ago); barrier makes all waves'
    // stages visible AND confirms all reads of bufp retired -> safe to flip.
    asm volatile("s_waitcnt vmcnt(0)" ::: "memory");
    __builtin_amdgcn_sched_barrier(0);
    __builtin_amdgcn_s_barrier();
    FENCE;
    cur ^= 1;
  }

  // epilogue: D row = fq*4 + r (within frag), col = fr
#pragma unroll
  for (int n = 0; n < 4; ++n) {
    const int col = col0 + wn * 64 + n * 16 + fr;
    const float bb = bias[col];
#pragma unroll
    for (int m = 0; m < 8; ++m) {
      const int rowb = row0 + wm * 128 + m * 16 + fq * 4;
#pragma unroll
      for (int r = 0; r < 4; ++r) {
        float e = exp2f((acc[m][n][r] + bb) * 1.44269504088896340736f);
        expout[(size_t)(rowb + r) * NV + col] = (bf16_t)e;
      }
    }
  }
}

// ---------------- marginals via indicator MFMA GEMM ----------------
// partials[ks][row][bucket] = sum over k in split ks of exp[row][k] * S^T[bucket][k]
__global__ __launch_bounds__(256)
void marginal_mfma_kernel(const bf16_t* __restrict__ expbuf, const bf16_t* __restrict__ st,
                          float* __restrict__ part) {
  __shared__ bf16_t sE[128][32];  // 8 KB
  __shared__ bf16_t sS[48][32];   // 3 KB

  const int t    = threadIdx.x;
  const int lane = t & 63;
  const int wv   = t >> 6;

  const int rt = blockIdx.x >> 4;        // row tile 0..31
  const int ks = blockIdx.x & (KSPLIT - 1);
  const int row0 = rt * 128;
  const int kbase = ks * (NV / KSPLIT);  // 512-state range

  const int srow = t >> 2;
  const int skel = (t & 3) * 8;
  const bf16_t* ep0 = expbuf + (size_t)(row0 + srow) * NV + kbase + skel;
  const bf16_t* ep1 = ep0 + (size_t)64 * NV;
  const bf16_t* sp0 = st + (size_t)srow * NV + kbase + skel;   // valid for t<192
  bf16_t* se0 = &sE[0][0] + (wv * 64) * 8;
  bf16_t* se1 = &sE[0][0] + (256 + wv * 64) * 8;
  bf16_t* ss0 = &sS[0][0] + (wv * 64) * 8;

  const int fr = lane & 15;
  const int fq = lane >> 4;

  f32x4 acc[2][3] = {};

  for (int kk = 0; kk < NV / KSPLIT; kk += 32) {
    GLL(ep0 + kk, se0);
    GLL(ep1 + kk, se1);
    if (wv < 3) GLL(sp0 + kk, ss0);
    __syncthreads();

    bf16x8 af[2], bg[3];
#pragma unroll
    for (int m = 0; m < 2; ++m)
      af[m] = *(const bf16x8*)&sE[wv * 32 + m * 16 + fr][fq * 8];
#pragma unroll
    for (int n = 0; n < 3; ++n)
      bg[n] = *(const bf16x8*)&sS[n * 16 + fr][fq * 8];
#pragma unroll
    for (int m = 0; m < 2; ++m)
#pragma unroll
      for (int n = 0; n < 3; ++n)
        acc[m][n] = __builtin_amdgcn_mfma_f32_16x16x32_bf16(af[m], bg[n], acc[m][n], 0, 0, 0);
    __syncthreads();
  }

  // D layout: row = fq*4 + r, col = fr
  float* pbase = part + (size_t)ks * BROWS * 48;
#pragma unroll
  for (int m = 0; m < 2; ++m) {
    const int rowb = row0 + wv * 32 + m * 16 + fq * 4;
#pragma unroll
    for (int n = 0; n < 3; ++n) {
      const int bucket = n * 16 + fr;
#pragma unroll
      for (int r = 0; r < 4; ++r)
        pbase[(size_t)(rowb + r) * 48 + bucket] = acc[m][n][r];
    }
  }
}

// ---------------- reduce partials + normalize ----------------
__global__ __launch_bounds__(64)
void reduce_kernel(const float* __restrict__ part, float* __restrict__ out) {
  const int b = blockIdx.x;
  const int t = threadIdx.x;
  __shared__ float fin[48];
  if (t < 48) {
    float s = 0.f;
#pragma unroll
    for (int ks = 0; ks < KSPLIT; ++ks)
      s += part[((size_t)ks * BROWS + b) * 48 + t];
    fin[t] = s;
  }
  __syncthreads();
  if (t < 48) {
    float total = fin[0] + fin[1] + fin[2] + fin[3] + fin[4] + fin[5] + fin[6] + fin[7];
    out[(size_t)(t >> 3) * BROWS * 8 + (size_t)b * 8 + (t & 7)] = fin[t] / total;
  }
}

// ---------------- launch ----------------
extern "C" void kernel_launch(void* const* d_in, const int* in_sizes, int n_in,
                              void* d_out, int out_size, void* d_ws, size_t ws_size,
                              hipStream_t stream) {
  const float* E    = (const float*)d_in[0];
  const float* W    = (const float*)d_in[1];
  const float* bias = (const float*)d_in[2];
  const int*   vs   = (const int*)d_in[3];
  float* out = (float*)d_out;

  char* ws = (char*)d_ws;
  size_t off = 0;
  bf16_t* Eb     = (bf16_t*)(ws + off); off += (size_t)BROWS * KD * 2;        // 8 MB
  bf16_t* Wb     = (bf16_t*)(ws + off); off += (size_t)NV * KD * 2;           // 16 MB
  bf16_t* expbuf = (bf16_t*)(ws + off); off += (size_t)BROWS * NV * 2;        // 64 MB
  bf16_t* st     = (bf16_t*)(ws + off); off += (size_t)48 * NV * 2;           // 786 KB
  float*  part   = (float*)(ws + off);  off += (size_t)KSPLIT * BROWS * 48 * 4; // 12.6 MB

  build_st_kernel<<<(48 * NV + 255) / 256, 256, 0, stream>>>(vs, st);
  cvt_kernel<<<2048, 256, 0, stream>>>(E, Eb, BROWS * KD / 4);
  cvt_kernel<<<2048, 256, 0, stream>>>(W, Wb, NV * KD / 4);
  gemm_exp_kernel<<<512, 512, 0, stream>>>(Eb, Wb, bias, expbuf);
  marginal_mfma_kernel<<<32 * KSPLIT, 256, 0, stream>>>(expbuf, st, part);
  reduce_kernel<<<BROWS, 64, 0, stream>>>(part, out);
}

// Round 7
// 106.201 us; speedup vs baseline: 2.3575x; 1.1259x over previous
//
#include <hip/hip_runtime.h>
#include <hip/hip_bf16.h>
#include <cstdint>
#include <cstddef>

typedef __bf16 bf16_t;
typedef bf16_t bf16x8 __attribute__((ext_vector_type(8)));
typedef bf16_t bf16x4 __attribute__((ext_vector_type(4)));
typedef float  f32x4  __attribute__((ext_vector_type(4)));
typedef unsigned int u32;

#define BROWS 4096
#define NV    8192
#define KD    1024
#define NT    16    // GEMM K-tiles (1024 / 64)
#define ST    48    // marginal buckets (6 concepts x 8)
#define LOG2E 1.44269504088896340736f

// async global->LDS, 16B per lane; LDS dst is wave-uniform base + lane*16
#define GLL(gsrc, ldst) \
  __builtin_amdgcn_global_load_lds((const __attribute__((address_space(1))) u32*)(gsrc), \
                                   (__attribute__((address_space(3))) u32*)(ldst), 16, 0, 0)
#define FENCE asm volatile("" ::: "memory")

// ---------------- f32 -> bf16 conversion ----------------
__global__ void cvt_kernel(const float* __restrict__ src, bf16_t* __restrict__ dst, int n4) {
  int idx = blockIdx.x * blockDim.x + threadIdx.x;
  int stride = gridDim.x * blockDim.x;
  for (int i = idx; i < n4; i += stride) {
    float4 v = ((const float4*)src)[i];
    bf16x4 o;
    o[0] = (bf16_t)v.x; o[1] = (bf16_t)v.y; o[2] = (bf16_t)v.z; o[3] = (bf16_t)v.w;
    ((bf16x4*)dst)[i] = o;
  }
}

// ---------------- build S2^T: one-hot indicator, bf16 [48][NV], swizzle-baked ----
// s2t[b][ig] = indicator(digit_c(vs[ig ^ ((b&7)<<3)]) == d), b = c*8+d.
// The XOR bakes the 16B-chunk LDS swizzle so the GEMM can GLL-stage rows
// linearly and ds_read with addr-XOR ((b&7)<<4) (rule #21 both-sides).
__global__ void build_s2t_kernel(const int* __restrict__ vstate, bf16_t* __restrict__ s2t) {
  int g = blockIdx.x * blockDim.x + threadIdx.x;   // g = b*NV + ig
  if (g >= ST * NV) return;
  int b = g >> 13;
  int ig = g & (NV - 1);
  int c = b >> 3;
  int d = b & 7;
  int src = ig ^ ((b & 7) << 3);
  int dig = (vstate[src] >> (15 - 3 * c)) & 7;
  s2t[g] = (bf16_t)(dig == d ? 1.0f : 0.0f);
}

// ---------------- fused GEMM + exp + marginal ----------------
// Swapped operands: D[i=state][j=batch] = sum_k W[i][k] * E[j][k].
// 256x256 tile, BK=64, 8 waves (wm: 2 state-halves x wn: 4 batch-quarters),
// 128 KiB double-buffered LDS, R5 single-barrier pipelined K-loop.
// Epilogue (2 passes of 128 batch rows): exp(acc+bias) -> bf16x4 ds_write_b64
// into swizzled LDS exp-tile; indicator-MFMA vs staged S2^T slice ->
// part[stile][batch][48] f32 partials. expbuf eliminated entirely.
__global__ __launch_bounds__(512, 2)
void gemm_fused_kernel(const bf16_t* __restrict__ W, const bf16_t* __restrict__ E,
                       const float* __restrict__ bias, const bf16_t* __restrict__ s2t,
                       float* __restrict__ part) {
  __shared__ __align__(16) char lds[2][65536];
  #define AKH0 0
  #define AKH1 16384
  #define BKH0 32768
  #define BKH1 49152

  const int t    = threadIdx.x;
  const int lane = t & 63;
  const int wv   = t >> 6;      // 0..7
  const int wm   = wv >> 2;     // 0..1  (state half)
  const int wn   = wv & 3;      // 0..3  (batch quarter)
  const int fr   = lane & 15;
  const int fq   = lane >> 4;

  // XCD swizzle: 512 blocks % 8 == 0 -> simple form bijective
  int bid = blockIdx.x;
  int wg  = (bid & 7) * 64 + (bid >> 3);
  const int stile = wg >> 4;    // 0..31 (state tile)
  const int btile = wg & 15;    // 0..15 (batch tile)
  const int st0 = stile * 256;
  const int bt0 = btile * 256;

  // ---- staging geometry (A role = W states, B role = E batch) ----
  const int srow = lane >> 2;
  const int skel = ((lane & 3) ^ ((lane >> 3) & 3)) * 8;
  const bf16_t* aptr = W + (size_t)(st0 + wv * 32 + srow) * KD + skel;
  const bf16_t* bptr = E + (size_t)(bt0 + wv * 32 + srow) * KD + skel;
  const int dchunk = (wv * 2) * 1024;

  // ---- ds_read geometry (swizzled): phys = logical ^ ((row&6)<<3) ----
  const int xsw = (fr & 6) << 3;
  const int base_a = (((wm * 128 + fr) * 64 + fq * 16) ^ xsw);
  const int base_b = 32768 + (((wn * 64 + fr) * 64 + fq * 16) ^ xsw);

  f32x4 acc[8][4] = {};

  // ---- prologue: stage kt0, drain, barrier
  GLL(aptr, &lds[0][AKH0 + dchunk]);
  GLL(aptr + 16 * KD, &lds[0][AKH0 + dchunk + 1024]);
  GLL(bptr, &lds[0][BKH0 + dchunk]);
  GLL(bptr + 16 * KD, &lds[0][BKH0 + dchunk + 1024]);
  GLL(aptr + 32, &lds[0][AKH1 + dchunk]);
  GLL(aptr + 32 + 16 * KD, &lds[0][AKH1 + dchunk + 1024]);
  GLL(bptr + 32, &lds[0][BKH1 + dchunk]);
  GLL(bptr + 32 + 16 * KD, &lds[0][BKH1 + dchunk + 1024]);
  asm volatile("s_waitcnt vmcnt(0)" ::: "memory");
  __builtin_amdgcn_s_barrier();
  FENCE;

  int cur = 0;
  for (int kt = 0; kt < NT; ++kt) {
    const char* bufp = lds[cur];
    char* nbuf = lds[cur ^ 1];
    const bool pf = (kt + 1 < NT);

    bf16x8 a0[8], b0[4], a1[8], b1[4];

#pragma unroll
    for (int n = 0; n < 4; ++n)
      b0[n] = *(const bf16x8*)(bufp + base_b + n * 1024);
#pragma unroll
    for (int m = 0; m < 8; ++m)
      a0[m] = *(const bf16x8*)(bufp + base_a + m * 1024);

    if (pf) {
      const bf16_t* an = aptr + (kt + 1) * 64;
      const bf16_t* bn = bptr + (kt + 1) * 64;
      GLL(an, &nbuf[AKH0 + dchunk]);
      GLL(an + 16 * KD, &nbuf[AKH0 + dchunk + 1024]);
      GLL(bn, &nbuf[BKH0 + dchunk]);
      GLL(bn + 16 * KD, &nbuf[BKH0 + dchunk + 1024]);
      GLL(an + 32, &nbuf[AKH1 + dchunk]);
      GLL(an + 32 + 16 * KD, &nbuf[AKH1 + dchunk + 1024]);
      GLL(bn + 32, &nbuf[BKH1 + dchunk]);
      GLL(bn + 32 + 16 * KD, &nbuf[BKH1 + dchunk + 1024]);
    }

#pragma unroll
    for (int n = 0; n < 4; ++n)
      b1[n] = *(const bf16x8*)(bufp + base_b + 16384 + n * 1024);
#pragma unroll
    for (int m = 0; m < 8; ++m)
      a1[m] = *(const bf16x8*)(bufp + base_a + 16384 + m * 1024);

    __builtin_amdgcn_s_setprio(1);
#pragma unroll
    for (int m = 0; m < 8; ++m)
#pragma unroll
      for (int n = 0; n < 4; ++n)
        acc[m][n] = __builtin_amdgcn_mfma_f32_16x16x32_bf16(a0[m], b0[n], acc[m][n], 0, 0, 0);
#pragma unroll
    for (int m = 0; m < 8; ++m)
#pragma unroll
      for (int n = 0; n < 4; ++n)
        acc[m][n] = __builtin_amdgcn_mfma_f32_16x16x32_bf16(a1[m], b1[n], acc[m][n], 0, 0, 0);
    __builtin_amdgcn_s_setprio(0);

    asm volatile("s_waitcnt vmcnt(0)" ::: "memory");
    __builtin_amdgcn_sched_barrier(0);
    __builtin_amdgcn_s_barrier();
    FENCE;
    cur ^= 1;
  }

  // ================= fused epilogue =================
  // Stage S2^T slice (48 rows x 256 states = 24 KB, swizzle-baked) into lds[1].
  char* const ldsf = &lds[0][0];
  {
#pragma unroll
    for (int q = 0; q < 3; ++q) {
      const bf16_t* src = s2t + (size_t)(wv * 6 + q * 2 + (lane >> 5)) * NV
                          + st0 + (lane & 31) * 8;
      GLL(src, ldsf + 65536 + wv * 3072 + q * 1024);
    }
  }

  float* const ppart = part + ((size_t)stile * BROWS + bt0) * ST;

#pragma unroll
  for (int pass = 0; pass < 2; ++pass) {
    // writer waves for this 128-batch-row half: wn>>1 == pass
    if ((wn >> 1) == pass) {
#pragma unroll
      for (int m = 0; m < 8; ++m) {
        const float4 bb = *(const float4*)&bias[st0 + wm * 128 + m * 16 + fq * 4];
#pragma unroll
        for (int n = 0; n < 4; ++n) {
          bf16x4 ev;
          ev[0] = (bf16_t)exp2f((acc[m][n][0] + bb.x) * LOG2E);
          ev[1] = (bf16_t)exp2f((acc[m][n][1] + bb.y) * LOG2E);
          ev[2] = (bf16_t)exp2f((acc[m][n][2] + bb.z) * LOG2E);
          ev[3] = (bf16_t)exp2f((acc[m][n][3] + bb.w) * LOG2E);
          const int jh = (wn & 1) * 64 + n * 16 + fr;          // half-local batch row
          const int ib = (wm * 128 + m * 16 + fq * 4) * 2;     // state byte offset
          *(bf16x4*)(ldsf + jh * 512 + (ib ^ ((fr & 7) << 4))) = ev;
        }
      }
    }
    if (pass == 0) asm volatile("s_waitcnt vmcnt(0)" ::: "memory");  // S2T resident
    __syncthreads();

    // marginal MFMA: all 8 waves; wave wv owns batch rows [wv*16, wv*16+16)
    f32x4 acc2[3] = {{0.f,0.f,0.f,0.f},{0.f,0.f,0.f,0.f},{0.f,0.f,0.f,0.f}};
#pragma unroll
    for (int k2 = 0; k2 < 8; ++k2) {
      const int ko = (k2 * 64 + fq * 16) ^ ((fr & 7) << 4);
      const bf16x8 ea = *(const bf16x8*)(ldsf + (wv * 16 + fr) * 512 + ko);
#pragma unroll
      for (int n2 = 0; n2 < 3; ++n2) {
        const bf16x8 sb = *(const bf16x8*)(ldsf + 65536 + (n2 * 16 + fr) * 512 + ko);
        acc2[n2] = __builtin_amdgcn_mfma_f32_16x16x32_bf16(ea, sb, acc2[n2], 0, 0, 0);
      }
    }
    const int jg = pass * 128 + wv * 16 + fq * 4;   // tile-local batch row base
#pragma unroll
    for (int n2 = 0; n2 < 3; ++n2)
#pragma unroll
      for (int r = 0; r < 4; ++r)
        ppart[(size_t)(jg + r) * ST + n2 * 16 + fr] = acc2[n2][r];
    __syncthreads();   // reads done before pass1 overwrites exp-tile
  }
}

// ---------------- reduce partials over 32 state-tiles + normalize ----------------
__global__ __launch_bounds__(64)
void reduce_kernel(const float* __restrict__ part, float* __restrict__ out) {
  const int b = blockIdx.x;
  const int t = threadIdx.x;
  __shared__ float fin[ST];
  if (t < ST) {
    float s = 0.f;
#pragma unroll
    for (int mt = 0; mt < 32; ++mt)
      s += part[((size_t)mt * BROWS + b) * ST + t];
    fin[t] = s;
  }
  __syncthreads();
  if (t < ST) {
    float total = fin[0] + fin[1] + fin[2] + fin[3] + fin[4] + fin[5] + fin[6] + fin[7];
    out[(size_t)(t >> 3) * BROWS * 8 + (size_t)b * 8 + (t & 7)] = fin[t] / total;
  }
}

// ---------------- launch ----------------
extern "C" void kernel_launch(void* const* d_in, const int* in_sizes, int n_in,
                              void* d_out, int out_size, void* d_ws, size_t ws_size,
                              hipStream_t stream) {
  const float* E    = (const float*)d_in[0];
  const float* W    = (const float*)d_in[1];
  const float* bias = (const float*)d_in[2];
  const int*   vs   = (const int*)d_in[3];
  float* out = (float*)d_out;

  char* ws = (char*)d_ws;
  size_t off = 0;
  bf16_t* Eb   = (bf16_t*)(ws + off); off += (size_t)BROWS * KD * 2;           // 8 MB
  bf16_t* Wb   = (bf16_t*)(ws + off); off += (size_t)NV * KD * 2;              // 16 MB
  bf16_t* s2t  = (bf16_t*)(ws + off); off += (size_t)ST * NV * 2;              // 786 KB
  float*  part = (float*)(ws + off);  off += (size_t)32 * BROWS * ST * 4;      // 25 MB

  build_s2t_kernel<<<(ST * NV + 255) / 256, 256, 0, stream>>>(vs, s2t);
  cvt_kernel<<<2048, 256, 0, stream>>>(E, Eb, BROWS * KD / 4);
  cvt_kernel<<<2048, 256, 0, stream>>>(W, Wb, NV * KD / 4);
  gemm_fused_kernel<<<512, 512, 0, stream>>>(Wb, Eb, bias, s2t, part);
  reduce_kernel<<<BROWS, 64, 0, stream>>>(part, out);
}